// Round 1
// baseline (1080.581 us; speedup 1.0000x reference)
//
#include <hip/hip_runtime.h>

#define NTOK 8192
#define TROWS 16384
#define DM 1024
#define HID 4096
#define NEXP 8
#define BM 128
#define BK 64
#define LDK (BK + 8)          // +8 bf16 pad -> row stride 144B kills the 128B-stride bank conflict
#define MAX_TILES 136

typedef __bf16 bf16x8 __attribute__((ext_vector_type(8)));
typedef float  f32x4  __attribute__((ext_vector_type(4)));
typedef short  s16x4  __attribute__((ext_vector_type(4)));

__device__ __forceinline__ short f2bf(float f) {
  union { float f; unsigned u; } v; v.f = f;
  unsigned r = (v.u + 0x7fffu + ((v.u >> 16) & 1u)) >> 16;  // RNE
  return (short)r;
}

// meta layout (ints): [0:8) counts, [8:16) offs, [16:24) cursor, [24] ntiles,
// [32 + 3*s ..] tiles: (expert, row_start, rows_in_tile)
__global__ void k_meta(const int* __restrict__ ei, int* __restrict__ meta,
                       float* __restrict__ outCounts) {
  __shared__ int c[NEXP];
  int tid = threadIdx.x;
  if (tid < NEXP) c[tid] = 0;
  __syncthreads();
  for (int i = tid; i < TROWS; i += 256) atomicAdd(&c[ei[i]], 1);
  __syncthreads();
  if (tid == 0) {
    int off = 0, s = 0;
    for (int e = 0; e < NEXP; ++e) {
      int ce = c[e];
      meta[e] = ce;
      meta[8 + e] = off;
      meta[16 + e] = off;            // cursor starts at expert offset
      outCounts[e] = (float)ce;      // output 1: tokens_per_expert
      for (int r0 = 0; r0 < ce; r0 += BM) {
        meta[32 + 3*s]     = e;
        meta[32 + 3*s + 1] = off + r0;
        meta[32 + 3*s + 2] = (ce - r0 < BM) ? (ce - r0) : BM;
        ++s;
      }
      off += ce;
    }
    meta[24] = s;
    for (; s < MAX_TILES; ++s) {
      meta[32 + 3*s] = 0; meta[32 + 3*s + 1] = 0; meta[32 + 3*s + 2] = 0;
    }
  }
}

__global__ void k_scatter(const int* __restrict__ ei, int* __restrict__ meta,
                          int* __restrict__ rowmap) {
  int t = blockIdx.x * blockDim.x + threadIdx.x;
  if (t < TROWS) {
    int e = ei[t];
    int p = atomicAdd(&meta[16 + e], 1);
    rowmap[p] = t;   // flat slot; token = t>>1, weight = ew[t]
  }
}

// (NEXP, R, C) f32 -> (NEXP, C, R) bf16   (coalesced both sides via LDS tile)
__global__ void k_transpose(const float* __restrict__ in, short* __restrict__ out,
                            int R, int C) {
  __shared__ float t[32][33];
  int e = blockIdx.z;
  int r0 = blockIdx.y * 32, c0 = blockIdx.x * 32;
  const float* src = in + ((size_t)e * R + r0) * C + c0;
  for (int i = 0; i < 4; ++i)
    t[threadIdx.y + 8*i][threadIdx.x] = src[(size_t)(threadIdx.y + 8*i) * C + threadIdx.x];
  __syncthreads();
  short* dst = out + ((size_t)e * C + c0) * R + r0;
  for (int i = 0; i < 4; ++i)
    dst[(size_t)(threadIdx.y + 8*i) * R + threadIdx.x] = f2bf(t[threadIdx.x][threadIdx.y + 8*i]);
}

__global__ void k_cvt_x(const float* __restrict__ x, short* __restrict__ xb) {
  const int n4 = NTOK * DM / 4;
  for (int i = blockIdx.x * blockDim.x + threadIdx.x; i < n4; i += gridDim.x * blockDim.x) {
    f32x4 v = ((const f32x4*)x)[i];
    s16x4 s = { f2bf(v.x), f2bf(v.y), f2bf(v.z), f2bf(v.w) };
    ((s16x4*)xb)[i] = s;
  }
}

// GEMM1: h[row][n] = silu(x@w1) * (x@w3), ragged rows via tile table + rowmap gather.
// A: xb (tok-row, K=1024 contiguous). B: w1t/w3t (E, N=4096, K=1024) bf16 (B^T layout).
__global__ __launch_bounds__(256, 2) void k_gemm1(
    const short* __restrict__ xb, const short* __restrict__ w1t, const short* __restrict__ w3t,
    const int* __restrict__ rowmap, const int* __restrict__ meta, short* __restrict__ hbuf) {
  int slot = blockIdx.x;
  int rows = meta[32 + 3*slot + 2];
  if (rows <= 0) return;
  int e    = meta[32 + 3*slot];
  int row0 = meta[32 + 3*slot + 1];
  int bn   = blockIdx.y;             // 0..31 over HID

  __shared__ short lA [BM * LDK];
  __shared__ short lB1[BM * LDK];
  __shared__ short lB3[BM * LDK];

  int tid = threadIdx.x;
  int rr = tid >> 3, k8 = tid & 7;   // 8 threads per row, 16B each

  const short* aSrc[4];
  for (int p = 0; p < 4; ++p) {
    int r = rr + 32*p;
    int rc = r < rows ? r : rows - 1;       // clamp ragged tail (stores masked later)
    int tok = rowmap[row0 + rc] >> 1;
    aSrc[p] = xb + (size_t)tok * DM + k8 * 8;
  }
  const short* b1Src = w1t + ((size_t)e * HID + (size_t)bn * BM + rr) * DM + k8 * 8;
  const short* b3Src = w3t + ((size_t)e * HID + (size_t)bn * BM + rr) * DM + k8 * 8;

  f32x4 acc1[4][4], acc3[4][4];
  for (int i = 0; i < 4; ++i)
    for (int j = 0; j < 4; ++j) {
      acc1[i][j] = (f32x4){0.f, 0.f, 0.f, 0.f};
      acc3[i][j] = (f32x4){0.f, 0.f, 0.f, 0.f};
    }

  int l = tid & 63, w = tid >> 6;
  int wr = (w >> 1) * 64, wc = (w & 1) * 64;
  int lr = l & 15, lk = (l >> 4) * 8;

  for (int kt = 0; kt < DM; kt += BK) {
    for (int p = 0; p < 4; ++p) {
      int r = rr + 32*p;
      *(f32x4*)&lA [r*LDK + k8*8] = *(const f32x4*)(aSrc[p] + kt);
      *(f32x4*)&lB1[r*LDK + k8*8] = *(const f32x4*)(b1Src + (size_t)(32*p) * DM + kt);
      *(f32x4*)&lB3[r*LDK + k8*8] = *(const f32x4*)(b3Src + (size_t)(32*p) * DM + kt);
    }
    __syncthreads();
#pragma unroll
    for (int kk = 0; kk < BK; kk += 32) {
      bf16x8 a[4], b1[4], b3[4];
#pragma unroll
      for (int i = 0; i < 4; ++i) a[i]  = *(const bf16x8*)&lA [(wr + i*16 + lr)*LDK + kk + lk];
#pragma unroll
      for (int j = 0; j < 4; ++j) b1[j] = *(const bf16x8*)&lB1[(wc + j*16 + lr)*LDK + kk + lk];
#pragma unroll
      for (int j = 0; j < 4; ++j) b3[j] = *(const bf16x8*)&lB3[(wc + j*16 + lr)*LDK + kk + lk];
#pragma unroll
      for (int i = 0; i < 4; ++i)
#pragma unroll
        for (int j = 0; j < 4; ++j) {
          acc1[i][j] = __builtin_amdgcn_mfma_f32_16x16x32_bf16(a[i], b1[j], acc1[i][j], 0, 0, 0);
          acc3[i][j] = __builtin_amdgcn_mfma_f32_16x16x32_bf16(a[i], b3[j], acc3[i][j], 0, 0, 0);
        }
    }
    __syncthreads();
  }

  // epilogue: SwiGLU, bf16 store. C/D layout: col = lane&15, row = (lane>>4)*4 + q (m89)
  for (int i = 0; i < 4; ++i)
    for (int q = 0; q < 4; ++q) {
      int r = wr + i*16 + (l >> 4)*4 + q;
      if (r < rows) {
        size_t rowbase = (size_t)(row0 + r) * HID + (size_t)bn * BM + wc;
        for (int j = 0; j < 4; ++j) {
          float g  = acc1[i][j][q], u3 = acc3[i][j][q];
          float sv = g / (1.f + __expf(-g));
          hbuf[rowbase + j*16 + lr] = f2bf(sv * u3);
        }
      }
    }
}

// GEMM2: out[token] += weight * (h @ w2).  A: hbuf (T, K=4096). B: w2t (E, N=1024, K=4096).
__global__ __launch_bounds__(256, 2) void k_gemm2(
    const short* __restrict__ hbuf, const short* __restrict__ w2t,
    const int* __restrict__ rowmap, const int* __restrict__ meta,
    const float* __restrict__ ew, float* __restrict__ out) {
  int slot = blockIdx.x;
  int rows = meta[32 + 3*slot + 2];
  if (rows <= 0) return;
  int e    = meta[32 + 3*slot];
  int row0 = meta[32 + 3*slot + 1];
  int bn   = blockIdx.y;             // 0..7 over DM

  __shared__ short lA[BM * LDK];
  __shared__ short lB[BM * LDK];

  int tid = threadIdx.x;
  int rr = tid >> 3, k8 = tid & 7;

  const short* aSrc[4];
  for (int p = 0; p < 4; ++p) {
    int r = rr + 32*p;
    int rc = r < rows ? r : rows - 1;
    aSrc[p] = hbuf + (size_t)(row0 + rc) * HID + k8 * 8;
  }
  const short* bSrc = w2t + ((size_t)e * DM + (size_t)bn * BM + rr) * HID + k8 * 8;

  f32x4 acc[4][4];
  for (int i = 0; i < 4; ++i)
    for (int j = 0; j < 4; ++j) acc[i][j] = (f32x4){0.f, 0.f, 0.f, 0.f};

  int l = tid & 63, w = tid >> 6;
  int wr = (w >> 1) * 64, wc = (w & 1) * 64;
  int lr = l & 15, lk = (l >> 4) * 8;

  for (int kt = 0; kt < HID; kt += BK) {
    for (int p = 0; p < 4; ++p) {
      int r = rr + 32*p;
      *(f32x4*)&lA[r*LDK + k8*8] = *(const f32x4*)(aSrc[p] + kt);
      *(f32x4*)&lB[r*LDK + k8*8] = *(const f32x4*)(bSrc + (size_t)(32*p) * HID + kt);
    }
    __syncthreads();
#pragma unroll
    for (int kk = 0; kk < BK; kk += 32) {
      bf16x8 a[4], b[4];
#pragma unroll
      for (int i = 0; i < 4; ++i) a[i] = *(const bf16x8*)&lA[(wr + i*16 + lr)*LDK + kk + lk];
#pragma unroll
      for (int j = 0; j < 4; ++j) b[j] = *(const bf16x8*)&lB[(wc + j*16 + lr)*LDK + kk + lk];
#pragma unroll
      for (int i = 0; i < 4; ++i)
#pragma unroll
        for (int j = 0; j < 4; ++j)
          acc[i][j] = __builtin_amdgcn_mfma_f32_16x16x32_bf16(a[i], b[j], acc[i][j], 0, 0, 0);
    }
    __syncthreads();
  }

  for (int i = 0; i < 4; ++i)
    for (int q = 0; q < 4; ++q) {
      int r = wr + i*16 + (l >> 4)*4 + q;
      if (r < rows) {
        int t = rowmap[row0 + r];
        float wgt = ew[t];
        size_t obase = (size_t)(t >> 1) * DM + (size_t)bn * BM + wc;
        for (int j = 0; j < 4; ++j)
          atomicAdd(&out[obase + j*16 + lr], acc[i][j][q] * wgt);
      }
    }
}

extern "C" void kernel_launch(void* const* d_in, const int* in_sizes, int n_in,
                              void* d_out, int out_size, void* d_ws, size_t ws_size,
                              hipStream_t stream) {
  const float* x  = (const float*)d_in[0];
  const float* ew = (const float*)d_in[1];
  const int*   ei = (const int*)d_in[2];
  const float* w1 = (const float*)d_in[3];
  const float* w2 = (const float*)d_in[4];
  const float* w3 = (const float*)d_in[5];
  float* out = (float*)d_out;
  char*  ws  = (char*)d_ws;

  // workspace layout (bytes)
  short* w1t = (short*)(ws + 0);                    //  64 MB  (8,4096,1024) bf16
  short* w3t = (short*)(ws + 67108864);             //  64 MB
  short* w2t = (short*)(ws + 134217728);            //  64 MB  (8,1024,4096) bf16
  short* xb  = (short*)(ws + 201326592);            //  16 MB  (8192,1024) bf16
  short* hb  = (short*)(ws + 218103808);            // 128 MB  (16384,4096) bf16
  int*   meta   = (int*)(ws + 352321536);           //   8 KB
  int*   rowmap = (int*)(ws + 352321536 + 8192);    //  64 KB

  hipMemsetAsync(d_out, 0, (size_t)out_size * sizeof(float), stream);
  k_meta<<<1, 256, 0, stream>>>(ei, meta, out + (size_t)NTOK * DM);
  k_scatter<<<TROWS / 256, 256, 0, stream>>>(ei, meta, rowmap);
  k_transpose<<<dim3(HID/32, DM/32, NEXP), dim3(32, 8), 0, stream>>>(w1, w1t, DM, HID);
  k_transpose<<<dim3(HID/32, DM/32, NEXP), dim3(32, 8), 0, stream>>>(w3, w3t, DM, HID);
  k_transpose<<<dim3(DM/32, HID/32, NEXP), dim3(32, 8), 0, stream>>>(w2, w2t, HID, DM);
  k_cvt_x<<<2048, 256, 0, stream>>>(x, xb);
  k_gemm1<<<dim3(MAX_TILES, HID/BM), 256, 0, stream>>>(xb, w1t, w3t, rowmap, meta, hb);
  k_gemm2<<<dim3(MAX_TILES, DM/BM), 256, 0, stream>>>(hb, w2t, rowmap, meta, ew, out);
}